// Round 3
// baseline (594.177 us; speedup 1.0000x reference)
//
#include <hip/hip_runtime.h>

static constexpr int N = 100000;   // nodes
static constexpr int E = 1000000;  // edges
static constexpr int D = 64;       // feature dim
static constexpr int NB = 391;     // dst buckets of 256 nodes (391*256 = 100096 >= N)
static constexpr int CAP = 3072;   // per-bucket edge capacity (mean 2560, ~+10 sigma)
static constexpr int EPT = 16;     // edges per thread in k_part
static constexpr int PART_CHUNK = 256 * EPT;                       // 4096
static constexpr int PART_BLOCKS = (E + PART_CHUNK - 1) / PART_CHUNK;  // 245

// ---- cnt[dst] += 1 for every non-self edge (deg = cnt+1 incl. self loop) --
__global__ __launch_bounds__(256) void k_count(const int* __restrict__ ei,
                                               int* __restrict__ cnt) {
    int i = blockIdx.x * 256 + threadIdx.x;
    if (i < E) {
        int s = ei[i];       // src
        int t = ei[E + i];   // dst
        if (s != t) atomicAdd(&cnt[t], 1);
    }
}

// ---- h'[n,:] = rsqrt(deg[n]) * (x[n,:] @ W^T) -----------------------------
__global__ __launch_bounds__(256) void k_linear(const float* __restrict__ x,
                                                const float* __restrict__ w,
                                                const int* __restrict__ cnt,
                                                float* __restrict__ h) {
    __shared__ float Wt[D * D];      // Wt[k*64 + o] = w[o*64 + k]
    __shared__ float xs[32 * D];
    int tid = threadIdx.x;
    for (int i = tid; i < D * D; i += 256) {
        int o = i >> 6, k = i & 63;
        Wt[k * D + o] = w[i];
    }
    int base = blockIdx.x * 32;
    for (int i = tid; i < 32 * D; i += 256) {
        int node = base + (i >> 6);
        xs[i] = (node < N) ? x[node * D + (i & 63)] : 0.f;
    }
    __syncthreads();
    int wave = tid >> 6, lane = tid & 63;
    for (int r = 0; r < 8; ++r) {
        int li = wave * 8 + r;
        int node = base + li;
        if (node >= N) break;        // wave-uniform
        float acc = 0.f;
#pragma unroll
        for (int k = 0; k < D; ++k)
            acc = fmaf(xs[li * D + k], Wt[k * D + lane], acc);
        float sc = rsqrtf((float)(cnt[node] + 1));
        h[node * D + lane] = sc * acc;
    }
}

// ---- bucket partition: part[b*CAP + j] = src | (dst&255)<<17 --------------
// Per-block LDS histogram -> one global atomic per (block,bucket) to reserve
// a contiguous range -> grouped writes (few partial cache lines).
__global__ __launch_bounds__(256) void k_part(const int* __restrict__ ei,
                                              int* __restrict__ gcur,
                                              int* __restrict__ part) {
    __shared__ int cnt[NB];
    __shared__ int cur[NB];
    int tid = threadIdx.x;
    for (int b = tid; b < NB; b += 256) cnt[b] = 0;
    __syncthreads();
    int base = blockIdx.x * PART_CHUNK + tid;
    for (int k = 0; k < EPT; ++k) {           // phase A: local histogram
        int i = base + k * 256;
        if (i < E) {
            int s = ei[i], t = ei[E + i];
            if (s != t) atomicAdd(&cnt[t >> 8], 1);
        }
    }
    __syncthreads();
    for (int b = tid; b < NB; b += 256) {     // phase B: reserve ranges
        int c = cnt[b];
        int off = c ? atomicAdd(&gcur[b], c) : 0;
        cur[b] = b * CAP + off;
    }
    __syncthreads();
    for (int k = 0; k < EPT; ++k) {           // phase C: grouped scatter
        int i = base + k * 256;
        if (i < E) {
            int s = ei[i], t = ei[E + i];
            if (s != t) {
                int b = t >> 8;
                int pos = atomicAdd(&cur[b], 1);
                if (pos < (b + 1) * CAP)      // safety (never triggers)
                    part[pos] = s | ((t & 255) << 17);
            }
        }
    }
}

// ---- aggregate: one block per bucket, 64 KB LDS out-tile ------------------
// out[t,:] = dis[t] * (sum_{s in nbr(t)} h'[s,:] + h'[t,:]) + bias
__global__ __launch_bounds__(512) void k_agg(const int* __restrict__ gcur,
                                             const int* __restrict__ part,
                                             const int* __restrict__ cnt,
                                             const float* __restrict__ h,
                                             const float* __restrict__ bias,
                                             float* __restrict__ out) {
    __shared__ float tile[256 * D];           // 64 KB -> 2 blocks/CU
    int tid = threadIdx.x;
    int wave = tid >> 6, lane = tid & 63;
    int b = blockIdx.x;
    float4* t4 = (float4*)tile;
    for (int i = tid; i < 256 * D / 4; i += 512) t4[i] = make_float4(0, 0, 0, 0);
    __syncthreads();
    int en = gcur[b];
    en = en < CAP ? en : CAP;
    const int* pb = part + b * CAP;
    for (int e0 = wave * 64; e0 < en; e0 += 512) {
        int m = en - e0;
        int pk = 0;
        if (lane < m) pk = pb[e0 + lane];     // 64 packed edges, coalesced
        int iters = m < 64 ? m : 64;
        for (int k = 0; k < iters; ++k) {
            int spk = __shfl(pk, k);
            int s = spk & 131071;
            int tl = spk >> 17;
            atomicAdd(&tile[tl * D + lane], h[s * D + lane]);  // LDS f32 atomic
        }
    }
    __syncthreads();
    float bl = bias[lane];
    for (int r = wave * 32; r < wave * 32 + 32; ++r) {
        int g = b * 256 + r;
        if (g < N) {
            float dt = rsqrtf((float)(cnt[g] + 1));
            out[g * D + lane] = fmaf(dt, tile[r * D + lane] + h[g * D + lane], bl);
        }
    }
}

extern "C" void kernel_launch(void* const* d_in, const int* in_sizes, int n_in,
                              void* d_out, int out_size, void* d_ws, size_t ws_size,
                              hipStream_t stream) {
    const float* x    = (const float*)d_in[0];   // [N, 64]
    const int*   ei   = (const int*)d_in[1];     // [2, E]
    const float* w    = (const float*)d_in[2];   // [64, 64]
    const float* bias = (const float*)d_in[3];   // [64]
    float* out = (float*)d_out;                  // [N, 64]

    // workspace layout (16B aligned)
    char* ws = (char*)d_ws;
    int*   cnt  = (int*)(ws);                    // N ints        @ 0
    int*   gcur = (int*)(ws + 400000);           // NB ints       @ 400000
    int*   part = (int*)(ws + 401600);           // NB*CAP ints   @ 401600
    float* h    = (float*)(ws + 5206208);        // N*64 floats   @ 5206208

    hipMemsetAsync(ws, 0, 401600, stream);       // cnt + gcur
    k_count <<<(E + 255) / 256, 256, 0, stream>>>(ei, cnt);
    k_part  <<<PART_BLOCKS, 256, 0, stream>>>(ei, gcur, part);
    k_linear<<<(N + 31) / 32, 256, 0, stream>>>(x, w, cnt, h);
    k_agg   <<<NB, 512, 0, stream>>>(gcur, part, cnt, h, bias, out);
}

// Round 5
// 122.567 us; speedup vs baseline: 4.8478x; 4.8478x over previous
//
#include <hip/hip_runtime.h>
#include <hip/hip_bf16.h>

static constexpr int N = 100000;   // nodes
static constexpr int E = 1000000;  // edges
static constexpr int D = 64;       // feature dim
static constexpr int NB = 391;     // dst buckets of 256 nodes (391*256 >= N)
static constexpr int CAP = 3072;   // per-bucket edge capacity (mean 2560, ~+10 sigma)
static constexpr int PART_EPT = 8;
static constexpr int PART_CHUNK = 256 * PART_EPT;                        // 2048
static constexpr int PART_BLOCKS = (E + PART_CHUNK - 1) / PART_CHUNK;    // 489

// ---- bucket partition: part[...] = src | (dst&255)<<17 --------------------
// Block-local histogram -> one global atomic per (block,bucket) -> grouped
// writes (few partial cache lines, ~5 entries/segment).
__global__ __launch_bounds__(256) void k_part(const int* __restrict__ ei,
                                              int* __restrict__ gcur,
                                              int* __restrict__ part) {
    __shared__ int hcnt[NB];
    __shared__ int hcur[NB];
    int tid = threadIdx.x;
    for (int b = tid; b < NB; b += 256) hcnt[b] = 0;
    __syncthreads();
    int base = blockIdx.x * PART_CHUNK + tid;
    int ss[PART_EPT], tt[PART_EPT];
#pragma unroll
    for (int k = 0; k < PART_EPT; ++k) {
        int i = base + k * 256;
        int s = -1, t = 0;
        if (i < E) {
            s = ei[i];
            t = ei[E + i];
            if (s == t) s = -1;            // drop self loops
        }
        ss[k] = s; tt[k] = t;
        if (s >= 0) atomicAdd(&hcnt[t >> 8], 1);
    }
    __syncthreads();
    for (int b = tid; b < NB; b += 256) {
        int c = hcnt[b];
        hcur[b] = b * CAP + (c ? atomicAdd(&gcur[b], c) : 0);
    }
    __syncthreads();
#pragma unroll
    for (int k = 0; k < PART_EPT; ++k) {
        int s = ss[k];
        if (s >= 0) {
            int b = tt[k] >> 8;
            int pos = atomicAdd(&hcur[b], 1);
            if (pos < (b + 1) * CAP)       // safety, statistically never
                part[pos] = s | ((tt[k] & 255) << 17);
        }
    }
}

// ---- per-bucket CSR build in LDS: hist -> scan -> scatter -----------------
// Writes: cnt[n] (non-self in-degree), row_start[n] (abs offset into srcs),
// srcs (grouped by dst, contiguous per node). All heavy traffic L2-resident.
__global__ __launch_bounds__(512) void k_csr(const int* __restrict__ gcur,
                                             const int* __restrict__ part,
                                             int* __restrict__ cnt,
                                             int* __restrict__ row_start,
                                             int* __restrict__ srcs) {
    __shared__ int cntL[256];
    __shared__ int scanL[256];
    __shared__ int curL[256];
    int tid = threadIdx.x;
    int b = blockIdx.x;
    if (tid < 256) cntL[tid] = 0;
    __syncthreads();
    int en = gcur[b];
    en = en < CAP ? en : CAP;
    const int* pb = part + b * CAP;
    for (int i = tid; i < en; i += 512)
        atomicAdd(&cntL[pb[i] >> 17], 1);
    __syncthreads();
    if (tid < 256) scanL[tid] = cntL[tid];
    __syncthreads();
    for (int off = 1; off < 256; off <<= 1) {   // inclusive scan over 256
        int v = 0;
        if (tid < 256 && tid >= off) v = scanL[tid - off];
        __syncthreads();
        if (tid < 256) scanL[tid] += v;
        __syncthreads();
    }
    if (tid < 256) {
        int node = b * 256 + tid;
        int excl = scanL[tid] - cntL[tid];
        if (node < N) {
            row_start[node] = b * CAP + excl;
            cnt[node] = cntL[tid];
        }
        curL[tid] = excl;
    }
    __syncthreads();
    for (int i = tid; i < en; i += 512) {
        int e = pb[i];
        int pos = atomicAdd(&curL[e >> 17], 1);
        srcs[b * CAP + pos] = e & 0x1FFFF;
    }
}

// ---- h'[n,:] = bf16( rsqrt(deg[n]) * (x[n,:] @ W^T) ) ---------------------
// W rows live in 64 VGPRs per lane (L1-hot); x staged in LDS, read as float4
// broadcast. Last block writes the all-zero dummy row N (tail-slot target).
__global__ __launch_bounds__(256) void k_linear(const float* __restrict__ x,
                                                const float* __restrict__ w,
                                                const int* __restrict__ cnt,
                                                __hip_bfloat16* __restrict__ hb) {
    int tid = threadIdx.x, lane = tid & 63, wave = tid >> 6;
    int base = blockIdx.x * 32;
    if (base >= N) {                       // dummy zero row
        if (tid < 64) hb[N * D + tid] = __hip_bfloat16(0.f);
        return;
    }
    __shared__ float xs[32 * D];           // 8 KB
    for (int i = tid; i < 32 * D; i += 256) {
        int node = base + (i >> 6);
        xs[i] = (node < N) ? x[node * D + (i & 63)] : 0.f;
    }
    float wr[64];                          // W row `lane` in registers
#pragma unroll
    for (int k4 = 0; k4 < 64; k4 += 4) {
        float4 v = *reinterpret_cast<const float4*>(&w[lane * 64 + k4]);
        wr[k4] = v.x; wr[k4 + 1] = v.y; wr[k4 + 2] = v.z; wr[k4 + 3] = v.w;
    }
    __syncthreads();
    for (int r = 0; r < 8; ++r) {
        int li = wave * 8 + r;
        int node = base + li;
        if (node >= N) break;              // wave-uniform
        float acc = 0.f;
#pragma unroll
        for (int k4 = 0; k4 < 64; k4 += 4) {
            float4 xv = *reinterpret_cast<const float4*>(&xs[li * 64 + k4]);
            acc = fmaf(xv.x, wr[k4], acc);
            acc = fmaf(xv.y, wr[k4 + 1], acc);
            acc = fmaf(xv.z, wr[k4 + 2], acc);
            acc = fmaf(xv.w, wr[k4 + 3], acc);
        }
        float sc = rsqrtf((float)(cnt[node] + 1));
        hb[node * D + lane] = __float2bfloat16(sc * acc);
    }
}

// ---- aggregate: one wave per node, 8 edges in flight ----------------------
// Lane L = (octet q=L>>3, sub l=L&7): octet q handles edge k0+q, lane loads
// 16B (8 bf16 dims) of that edge's h' row. f32 accumulate, cross-octet
// shfl reduce, single coalesced 256B out write.
__global__ __launch_bounds__(256) void k_agg(const int* __restrict__ row_start,
                                             const int* __restrict__ cnt,
                                             const int* __restrict__ srcs,
                                             const ushort* __restrict__ hb,
                                             const float* __restrict__ bias,
                                             float* __restrict__ out) {
    int g = blockIdx.x * 256 + threadIdx.x;
    int t = g >> 6, lane = g & 63;
    if (t >= N) return;
    int q = lane >> 3, l = lane & 7;
    int base = row_start[t];
    int len = cnt[t];
    float acc[8];
#pragma unroll
    for (int i = 0; i < 8; ++i) acc[i] = 0.f;

    for (int k0 = 0; k0 < len; k0 += 8) {
        int idx = k0 + q;
        int s = (idx < len) ? srcs[base + idx] : N;   // N = zero row
        int4 v = *reinterpret_cast<const int4*>(hb + s * D + l * 8);
        acc[0] += __uint_as_float(((unsigned)v.x) << 16);
        acc[1] += __uint_as_float(((unsigned)v.x) & 0xffff0000u);
        acc[2] += __uint_as_float(((unsigned)v.y) << 16);
        acc[3] += __uint_as_float(((unsigned)v.y) & 0xffff0000u);
        acc[4] += __uint_as_float(((unsigned)v.z) << 16);
        acc[5] += __uint_as_float(((unsigned)v.z) & 0xffff0000u);
        acc[6] += __uint_as_float(((unsigned)v.w) << 16);
        acc[7] += __uint_as_float(((unsigned)v.w) & 0xffff0000u);
    }
#pragma unroll
    for (int i = 0; i < 8; ++i) {
        acc[i] += __shfl_down(acc[i], 32);
        acc[i] += __shfl_down(acc[i], 16);
        acc[i] += __shfl_down(acc[i], 8);
    }
    if (lane < 8) {                        // lanes 0..7 hold dims lane*8..+7
        int4 v = *reinterpret_cast<const int4*>(hb + t * D + lane * 8);
        acc[0] += __uint_as_float(((unsigned)v.x) << 16);
        acc[1] += __uint_as_float(((unsigned)v.x) & 0xffff0000u);
        acc[2] += __uint_as_float(((unsigned)v.y) << 16);
        acc[3] += __uint_as_float(((unsigned)v.y) & 0xffff0000u);
        acc[4] += __uint_as_float(((unsigned)v.z) << 16);
        acc[5] += __uint_as_float(((unsigned)v.z) & 0xffff0000u);
        acc[6] += __uint_as_float(((unsigned)v.w) << 16);
        acc[7] += __uint_as_float(((unsigned)v.w) & 0xffff0000u);
        float dt = rsqrtf((float)(len + 1));
        float4 ba = *reinterpret_cast<const float4*>(&bias[lane * 8]);
        float4 bb = *reinterpret_cast<const float4*>(&bias[lane * 8 + 4]);
        float4 o0, o1;
        o0.x = fmaf(dt, acc[0], ba.x);
        o0.y = fmaf(dt, acc[1], ba.y);
        o0.z = fmaf(dt, acc[2], ba.z);
        o0.w = fmaf(dt, acc[3], ba.w);
        o1.x = fmaf(dt, acc[4], bb.x);
        o1.y = fmaf(dt, acc[5], bb.y);
        o1.z = fmaf(dt, acc[6], bb.z);
        o1.w = fmaf(dt, acc[7], bb.w);
        *reinterpret_cast<float4*>(out + t * D + lane * 8) = o0;
        *reinterpret_cast<float4*>(out + t * D + lane * 8 + 4) = o1;
    }
}

extern "C" void kernel_launch(void* const* d_in, const int* in_sizes, int n_in,
                              void* d_out, int out_size, void* d_ws, size_t ws_size,
                              hipStream_t stream) {
    const float* x    = (const float*)d_in[0];   // [N, 64]
    const int*   ei   = (const int*)d_in[1];     // [2, E]
    const float* w    = (const float*)d_in[2];   // [64, 64]
    const float* bias = (const float*)d_in[3];   // [64]
    float* out = (float*)d_out;                  // [N, 64]

    // workspace layout (16B aligned)
    char* ws = (char*)d_ws;
    int*   gcur = (int*)(ws);                    // NB ints        @ 0
    int*   part = (int*)(ws + 1664);             // NB*CAP ints
    int*   srcs = (int*)(ws + 4806272);          // NB*CAP ints
    int*   cnt  = (int*)(ws + 9610880);          // N ints
    int*   rs   = (int*)(ws + 10010880);         // N ints
    __hip_bfloat16* hb = (__hip_bfloat16*)(ws + 10410880);  // (N+1)*64 bf16

    hipMemsetAsync(gcur, 0, NB * sizeof(int), stream);
    k_part  <<<PART_BLOCKS, 256, 0, stream>>>(ei, gcur, part);
    k_csr   <<<NB, 512, 0, stream>>>(gcur, part, cnt, rs, srcs);
    k_linear<<<(N + 31) / 32 + 1, 256, 0, stream>>>(x, w, cnt, hb);
    k_agg   <<<(N * 64) / 256, 256, 0, stream>>>(rs, cnt, srcs, (const ushort*)hb, bias, out);
}

// Round 7
// 101.383 us; speedup vs baseline: 5.8607x; 1.2089x over previous
//
#include <hip/hip_runtime.h>
#include <hip/hip_bf16.h>

static constexpr int N = 100000;   // nodes
static constexpr int E = 1000000;  // edges
static constexpr int D = 64;       // feature dim
static constexpr int NB = 391;     // dst buckets of 256 nodes (391*256 >= N)
static constexpr int CAP = 3072;   // per-bucket edge capacity (mean 2560, ~+10 sigma)
static constexpr int PART_EPT = 32;
static constexpr int PART_CHUNK = 256 * PART_EPT;                        // 8192
static constexpr int PART_BLOCKS = (E + PART_CHUNK - 1) / PART_CHUNK;    // 123

typedef __attribute__((ext_vector_type(8))) short bf16x8;
typedef __attribute__((ext_vector_type(4))) float f32x4;

__device__ inline ushort f2bf(float f) {     // RNE f32 -> bf16 bits
    unsigned u = __float_as_uint(f);
    return (ushort)((u + 0x7fffu + ((u >> 16) & 1u)) >> 16);
}

// ---- bucket partition + (block 0) W f32->bf16 conversion ------------------
// part[...] = src | (dst&255)<<17, grouped per (block,bucket) so global
// writes land in ~21-entry contiguous segments (low partial-line writeback).
__global__ __launch_bounds__(256) void k_part(const int* __restrict__ ei,
                                              const float* __restrict__ w,
                                              int* __restrict__ gcur,
                                              int* __restrict__ part,
                                              ushort* __restrict__ wbf) {
    __shared__ int hcnt[NB];
    __shared__ int hcur[NB];
    int tid = threadIdx.x;
    if (blockIdx.x == 0) {                    // W -> bf16 (4096 elems)
        int i0 = tid * 16;
#pragma unroll
        for (int c = 0; c < 4; ++c) {
            float4 v = *reinterpret_cast<const float4*>(w + i0 + c * 4);
            ushort4 o;
            o.x = f2bf(v.x); o.y = f2bf(v.y); o.z = f2bf(v.z); o.w = f2bf(v.w);
            *reinterpret_cast<ushort4*>(wbf + i0 + c * 4) = o;
        }
    }
    for (int b = tid; b < NB; b += 256) hcnt[b] = 0;
    __syncthreads();
    int base = blockIdx.x * PART_CHUNK + tid;
    for (int k = 0; k < PART_EPT; ++k) {      // phase A: local histogram
        int i = base + k * 256;
        if (i < E) {
            int s = ei[i], t = ei[E + i];
            if (s != t) atomicAdd(&hcnt[t >> 8], 1);
        }
    }
    __syncthreads();
    for (int b = tid; b < NB; b += 256) {     // phase B: reserve ranges
        int c = hcnt[b];
        hcur[b] = b * CAP + (c ? atomicAdd(&gcur[b], c) : 0);
    }
    __syncthreads();
    for (int k = 0; k < PART_EPT; ++k) {      // phase C: re-read + scatter
        int i = base + k * 256;
        if (i < E) {
            int s = ei[i], t = ei[E + i];
            if (s != t) {
                int b = t >> 8;
                int pos = atomicAdd(&hcur[b], 1);
                if (pos < (b + 1) * CAP)      // safety, statistically never
                    part[pos] = s | ((t & 255) << 17);
            }
        }
    }
}

// ---- per-bucket CSR build in LDS: hist -> scan -> scatter -----------------
__global__ __launch_bounds__(512) void k_csr(const int* __restrict__ gcur,
                                             const int* __restrict__ part,
                                             int* __restrict__ cnt,
                                             int* __restrict__ row_start,
                                             int* __restrict__ srcs) {
    __shared__ int cntL[256];
    __shared__ int scanL[256];
    __shared__ int curL[256];
    int tid = threadIdx.x;
    int b = blockIdx.x;
    if (tid < 256) cntL[tid] = 0;
    __syncthreads();
    int en = gcur[b];
    en = en < CAP ? en : CAP;
    const int* pb = part + b * CAP;
    for (int i = tid; i < en; i += 512)
        atomicAdd(&cntL[pb[i] >> 17], 1);
    __syncthreads();
    if (tid < 256) scanL[tid] = cntL[tid];
    __syncthreads();
    for (int off = 1; off < 256; off <<= 1) {   // inclusive scan over 256
        int v = 0;
        if (tid < 256 && tid >= off) v = scanL[tid - off];
        __syncthreads();
        if (tid < 256) scanL[tid] += v;
        __syncthreads();
    }
    if (tid < 256) {
        int node = b * 256 + tid;
        int excl = scanL[tid] - cntL[tid];
        if (node < N) {
            row_start[node] = b * CAP + excl;
            cnt[node] = cntL[tid];
        }
        curL[tid] = excl;
    }
    __syncthreads();
    for (int i = tid; i < en; i += 512) {
        int e = pb[i];
        int pos = atomicAdd(&curL[e >> 17], 1);
        srcs[b * CAP + pos] = e & 0x1FFFF;
    }
}

// ---- h'[n,:] = bf16( rsqrt(deg[n]) * (x[n,:] @ W^T) )  via MFMA -----------
// One wave per 16-node tile. A = x-tile (f32 load -> RNE bf16), layout
// row=lane&15, k=(lane>>4)*8+j. B = wbf row (B^T k-contiguous, 16B load).
// 4 N-tiles x 2 K-steps = 8 mfma_f32_16x16x32_bf16. C/D: col=lane&15,
// row=(lane>>4)*4+reg (m89-verified). Fused rsqrt(deg) scale + bf16 store.
__global__ __launch_bounds__(256) void k_linear(const float* __restrict__ x,
                                                const ushort* __restrict__ wbf,
                                                const int* __restrict__ cnt,
                                                ushort* __restrict__ hb) {
    int tid = threadIdx.x;
    if (blockIdx.x == 0 && tid < 32)          // dummy zero row N (agg tail)
        reinterpret_cast<int*>(hb + N * D)[tid] = 0;
    int lane = tid & 63, wave = tid >> 6;
    int tbase = blockIdx.x * 64 + wave * 16;
    if (tbase >= N) return;                   // wave-uniform
    int r15 = lane & 15, g4 = lane >> 4;
    int arow = tbase + r15;
    if (arow >= N) arow = N - 1;              // clamped load, store guarded
    bf16x8 afr[2];
#pragma unroll
    for (int ks = 0; ks < 2; ++ks) {
        const float* ap = x + arow * 64 + ks * 32 + g4 * 8;
        float4 v0 = *reinterpret_cast<const float4*>(ap);
        float4 v1 = *reinterpret_cast<const float4*>(ap + 4);
        bf16x8 a;
        a[0] = (short)f2bf(v0.x); a[1] = (short)f2bf(v0.y);
        a[2] = (short)f2bf(v0.z); a[3] = (short)f2bf(v0.w);
        a[4] = (short)f2bf(v1.x); a[5] = (short)f2bf(v1.y);
        a[6] = (short)f2bf(v1.z); a[7] = (short)f2bf(v1.w);
        afr[ks] = a;
    }
    f32x4 acc[4] = {};
#pragma unroll
    for (int nt = 0; nt < 4; ++nt)
#pragma unroll
        for (int ks = 0; ks < 2; ++ks) {
            bf16x8 b = *reinterpret_cast<const bf16x8*>(
                wbf + (nt * 16 + r15) * 64 + ks * 32 + g4 * 8);
            acc[nt] = __builtin_amdgcn_mfma_f32_16x16x32_bf16(afr[ks], b, acc[nt], 0, 0, 0);
        }
#pragma unroll
    for (int r = 0; r < 4; ++r) {
        int node = tbase + g4 * 4 + r;
        if (node < N) {
            float dt = rsqrtf((float)(cnt[node] + 1));
#pragma unroll
            for (int nt = 0; nt < 4; ++nt)
                hb[node * D + nt * 16 + r15] = f2bf(dt * acc[nt][r]);
        }
    }
}

// ---- aggregate: one wave per node, 8 edges in flight ----------------------
__global__ __launch_bounds__(256) void k_agg(const int* __restrict__ row_start,
                                             const int* __restrict__ cnt,
                                             const int* __restrict__ srcs,
                                             const ushort* __restrict__ hb,
                                             const float* __restrict__ bias,
                                             float* __restrict__ out) {
    int g = blockIdx.x * 256 + threadIdx.x;
    int t = g >> 6, lane = g & 63;
    if (t >= N) return;
    int q = lane >> 3, l = lane & 7;
    int base = row_start[t];
    int len = cnt[t];
    float acc[8];
#pragma unroll
    for (int i = 0; i < 8; ++i) acc[i] = 0.f;

    for (int k0 = 0; k0 < len; k0 += 8) {
        int idx = k0 + q;
        int s = (idx < len) ? srcs[base + idx] : N;   // N = zero row
        int4 v = *reinterpret_cast<const int4*>(hb + s * D + l * 8);
        acc[0] += __uint_as_float(((unsigned)v.x) << 16);
        acc[1] += __uint_as_float(((unsigned)v.x) & 0xffff0000u);
        acc[2] += __uint_as_float(((unsigned)v.y) << 16);
        acc[3] += __uint_as_float(((unsigned)v.y) & 0xffff0000u);
        acc[4] += __uint_as_float(((unsigned)v.z) << 16);
        acc[5] += __uint_as_float(((unsigned)v.z) & 0xffff0000u);
        acc[6] += __uint_as_float(((unsigned)v.w) << 16);
        acc[7] += __uint_as_float(((unsigned)v.w) & 0xffff0000u);
    }
#pragma unroll
    for (int i = 0; i < 8; ++i) {
        acc[i] += __shfl_down(acc[i], 32);
        acc[i] += __shfl_down(acc[i], 16);
        acc[i] += __shfl_down(acc[i], 8);
    }
    if (lane < 8) {                        // lanes 0..7 hold dims lane*8..+7
        int4 v = *reinterpret_cast<const int4*>(hb + t * D + lane * 8);
        acc[0] += __uint_as_float(((unsigned)v.x) << 16);
        acc[1] += __uint_as_float(((unsigned)v.x) & 0xffff0000u);
        acc[2] += __uint_as_float(((unsigned)v.y) << 16);
        acc[3] += __uint_as_float(((unsigned)v.y) & 0xffff0000u);
        acc[4] += __uint_as_float(((unsigned)v.z) << 16);
        acc[5] += __uint_as_float(((unsigned)v.z) & 0xffff0000u);
        acc[6] += __uint_as_float(((unsigned)v.w) << 16);
        acc[7] += __uint_as_float(((unsigned)v.w) & 0xffff0000u);
        float dt = rsqrtf((float)(len + 1));
        float4 ba = *reinterpret_cast<const float4*>(&bias[lane * 8]);
        float4 bb = *reinterpret_cast<const float4*>(&bias[lane * 8 + 4]);
        float4 o0, o1;
        o0.x = fmaf(dt, acc[0], ba.x);
        o0.y = fmaf(dt, acc[1], ba.y);
        o0.z = fmaf(dt, acc[2], ba.z);
        o0.w = fmaf(dt, acc[3], ba.w);
        o1.x = fmaf(dt, acc[4], bb.x);
        o1.y = fmaf(dt, acc[5], bb.y);
        o1.z = fmaf(dt, acc[6], bb.z);
        o1.w = fmaf(dt, acc[7], bb.w);
        *reinterpret_cast<float4*>(out + t * D + lane * 8) = o0;
        *reinterpret_cast<float4*>(out + t * D + lane * 8 + 4) = o1;
    }
}

extern "C" void kernel_launch(void* const* d_in, const int* in_sizes, int n_in,
                              void* d_out, int out_size, void* d_ws, size_t ws_size,
                              hipStream_t stream) {
    const float* x    = (const float*)d_in[0];   // [N, 64]
    const int*   ei   = (const int*)d_in[1];     // [2, E]
    const float* w    = (const float*)d_in[2];   // [64, 64]
    const float* bias = (const float*)d_in[3];   // [64]
    float* out = (float*)d_out;                  // [N, 64]

    // workspace layout (16B aligned)
    char* ws = (char*)d_ws;
    int*    gcur = (int*)(ws);                   // NB ints          @ 0
    ushort* wbf  = (ushort*)(ws + 1664);         // 4096 bf16 (8 KB)
    int*    part = (int*)(ws + 9856);            // NB*CAP ints
    int*    srcs = (int*)(ws + 4814464);         // NB*CAP ints
    int*    cnt  = (int*)(ws + 9619072);         // N ints
    int*    rs   = (int*)(ws + 10019072);        // N ints
    ushort* hb   = (ushort*)(ws + 10419072);     // (N+1)*64 bf16

    hipMemsetAsync(gcur, 0, 1664, stream);
    k_part  <<<PART_BLOCKS, 256, 0, stream>>>(ei, w, gcur, part, wbf);
    k_csr   <<<NB, 512, 0, stream>>>(gcur, part, cnt, rs, srcs);
    k_linear<<<(N + 63) / 64, 256, 0, stream>>>(x, wbf, cnt, hb);
    k_agg   <<<(N * 64) / 256, 256, 0, stream>>>(rs, cnt, srcs, hb, bias, out);
}

// Round 8
// 88.774 us; speedup vs baseline: 6.6931x; 1.1420x over previous
//
#include <hip/hip_runtime.h>
#include <hip/hip_bf16.h>

static constexpr int N = 100000;   // nodes
static constexpr int E = 1000000;  // edges
static constexpr int D = 64;       // feature dim
static constexpr int NB = 391;     // dst buckets of 256 nodes (391*256 >= N)
static constexpr int CAP = 3072;   // per-bucket edge capacity (mean 2560, ~+10 sigma)
static constexpr int PART_EPT = 8;
static constexpr int PART_CHUNK = 256 * PART_EPT;                        // 2048
static constexpr int PART_BLOCKS = (E + PART_CHUNK - 1) / PART_CHUNK;    // 489

typedef __attribute__((ext_vector_type(8))) short bf16x8;
typedef __attribute__((ext_vector_type(4))) float f32x4;

__device__ inline ushort f2bf(float f) {     // RNE f32 -> bf16 bits
    unsigned u = __float_as_uint(f);
    return (ushort)((u + 0x7fffu + ((u >> 16) & 1u)) >> 16);
}

// ---- bucket partition + (block 0) W f32->bf16 conversion ------------------
// part[...] = src | (dst&255)<<17, grouped per (block,bucket) so global
// writes land in ~5-entry contiguous segments. 489 blocks -> ~2 blocks/CU.
__global__ __launch_bounds__(256) void k_part(const int* __restrict__ ei,
                                              const float* __restrict__ w,
                                              int* __restrict__ gcur,
                                              int* __restrict__ part,
                                              ushort* __restrict__ wbf) {
    __shared__ int hcnt[NB];
    __shared__ int hcur[NB];
    int tid = threadIdx.x;
    if (blockIdx.x == 0) {                    // W -> bf16 (4096 elems)
        int i0 = tid * 16;
#pragma unroll
        for (int c = 0; c < 4; ++c) {
            float4 v = *reinterpret_cast<const float4*>(w + i0 + c * 4);
            ushort4 o;
            o.x = f2bf(v.x); o.y = f2bf(v.y); o.z = f2bf(v.z); o.w = f2bf(v.w);
            *reinterpret_cast<ushort4*>(wbf + i0 + c * 4) = o;
        }
    }
    for (int b = tid; b < NB; b += 256) hcnt[b] = 0;
    __syncthreads();
    int base = blockIdx.x * PART_CHUNK + tid;
    int ss[PART_EPT], tt[PART_EPT];
#pragma unroll
    for (int k = 0; k < PART_EPT; ++k) {      // phase A: local histogram
        int i = base + k * 256;
        int s = -1, t = 0;
        if (i < E) {
            s = ei[i];
            t = ei[E + i];
            if (s == t) s = -1;               // drop self loops
        }
        ss[k] = s; tt[k] = t;
        if (s >= 0) atomicAdd(&hcnt[t >> 8], 1);
    }
    __syncthreads();
    for (int b = tid; b < NB; b += 256) {     // phase B: reserve ranges
        int c = hcnt[b];
        hcur[b] = b * CAP + (c ? atomicAdd(&gcur[b], c) : 0);
    }
    __syncthreads();
#pragma unroll
    for (int k = 0; k < PART_EPT; ++k) {      // phase C: grouped scatter
        int s = ss[k];
        if (s >= 0) {
            int b = tt[k] >> 8;
            int pos = atomicAdd(&hcur[b], 1);
            if (pos < (b + 1) * CAP)          // safety, statistically never
                part[pos] = s | ((tt[k] & 255) << 17);
        }
    }
}

// ---- per-bucket CSR build in LDS: hist -> scan -> scatter -----------------
__global__ __launch_bounds__(512) void k_csr(const int* __restrict__ gcur,
                                             const int* __restrict__ part,
                                             int* __restrict__ cnt,
                                             int* __restrict__ row_start,
                                             int* __restrict__ srcs) {
    __shared__ int cntL[256];
    __shared__ int scanL[256];
    __shared__ int curL[256];
    int tid = threadIdx.x;
    int b = blockIdx.x;
    if (tid < 256) cntL[tid] = 0;
    __syncthreads();
    int en = gcur[b];
    en = en < CAP ? en : CAP;
    const int* pb = part + b * CAP;
    for (int i = tid; i < en; i += 512)
        atomicAdd(&cntL[pb[i] >> 17], 1);
    __syncthreads();
    if (tid < 256) scanL[tid] = cntL[tid];
    __syncthreads();
    for (int off = 1; off < 256; off <<= 1) {   // inclusive scan over 256
        int v = 0;
        if (tid < 256 && tid >= off) v = scanL[tid - off];
        __syncthreads();
        if (tid < 256) scanL[tid] += v;
        __syncthreads();
    }
    if (tid < 256) {
        int node = b * 256 + tid;
        int excl = scanL[tid] - cntL[tid];
        if (node < N) {
            row_start[node] = b * CAP + excl;
            cnt[node] = cntL[tid];
        }
        curL[tid] = excl;
    }
    __syncthreads();
    for (int i = tid; i < en; i += 512) {
        int e = pb[i];
        int pos = atomicAdd(&curL[e >> 17], 1);
        srcs[b * CAP + pos] = e & 0x1FFFF;
    }
}

// ---- h'[n,:] = bf16( rsqrt(deg[n]) * (x[n,:] @ W^T) )  via MFMA -----------
__global__ __launch_bounds__(256) void k_linear(const float* __restrict__ x,
                                                const ushort* __restrict__ wbf,
                                                const int* __restrict__ cnt,
                                                ushort* __restrict__ hb) {
    int tid = threadIdx.x;
    if (blockIdx.x == 0 && tid < 32)          // dummy zero row N (agg tail)
        reinterpret_cast<int*>(hb + N * D)[tid] = 0;
    int lane = tid & 63, wave = tid >> 6;
    int tbase = blockIdx.x * 64 + wave * 16;
    if (tbase >= N) return;                   // wave-uniform
    int r15 = lane & 15, g4 = lane >> 4;
    int arow = tbase + r15;
    if (arow >= N) arow = N - 1;              // clamped load, store guarded
    bf16x8 afr[2];
#pragma unroll
    for (int ks = 0; ks < 2; ++ks) {
        const float* ap = x + arow * 64 + ks * 32 + g4 * 8;
        float4 v0 = *reinterpret_cast<const float4*>(ap);
        float4 v1 = *reinterpret_cast<const float4*>(ap + 4);
        bf16x8 a;
        a[0] = (short)f2bf(v0.x); a[1] = (short)f2bf(v0.y);
        a[2] = (short)f2bf(v0.z); a[3] = (short)f2bf(v0.w);
        a[4] = (short)f2bf(v1.x); a[5] = (short)f2bf(v1.y);
        a[6] = (short)f2bf(v1.z); a[7] = (short)f2bf(v1.w);
        afr[ks] = a;
    }
    f32x4 acc[4] = {};
#pragma unroll
    for (int nt = 0; nt < 4; ++nt)
#pragma unroll
        for (int ks = 0; ks < 2; ++ks) {
            bf16x8 b = *reinterpret_cast<const bf16x8*>(
                wbf + (nt * 16 + r15) * 64 + ks * 32 + g4 * 8);
            acc[nt] = __builtin_amdgcn_mfma_f32_16x16x32_bf16(afr[ks], b, acc[nt], 0, 0, 0);
        }
#pragma unroll
    for (int r = 0; r < 4; ++r) {
        int node = tbase + g4 * 4 + r;
        if (node < N) {
            float dt = rsqrtf((float)(cnt[node] + 1));
#pragma unroll
            for (int nt = 0; nt < 4; ++nt)
                hb[node * D + nt * 16 + r15] = f2bf(dt * acc[nt][r]);
        }
    }
}

// ---- aggregate: one wave per node, software-pipelined gather --------------
// Octet q handles edge k0+q; lane loads 16B (8 bf16 dims) of that edge's row.
// Round k+1's srcs+row loads issue BEFORE round k's unpack-adds consume, so
// both of the (typical deg~10 -> 2) rounds' gathers are in flight at once.
#define ACC8(v)                                                    \
    acc[0] += __uint_as_float(((unsigned)(v).x) << 16);            \
    acc[1] += __uint_as_float(((unsigned)(v).x) & 0xffff0000u);    \
    acc[2] += __uint_as_float(((unsigned)(v).y) << 16);            \
    acc[3] += __uint_as_float(((unsigned)(v).y) & 0xffff0000u);    \
    acc[4] += __uint_as_float(((unsigned)(v).z) << 16);            \
    acc[5] += __uint_as_float(((unsigned)(v).z) & 0xffff0000u);    \
    acc[6] += __uint_as_float(((unsigned)(v).w) << 16);            \
    acc[7] += __uint_as_float(((unsigned)(v).w) & 0xffff0000u);

__global__ __launch_bounds__(256) void k_agg(const int* __restrict__ row_start,
                                             const int* __restrict__ cnt,
                                             const int* __restrict__ srcs,
                                             const ushort* __restrict__ hb,
                                             const float* __restrict__ bias,
                                             float* __restrict__ out) {
    int g = blockIdx.x * 256 + threadIdx.x;
    int t = g >> 6, lane = g & 63;
    if (t >= N) return;
    int q = lane >> 3, l = lane & 7;
    int base = row_start[t];
    int len = cnt[t];
    float acc[8];
#pragma unroll
    for (int i = 0; i < 8; ++i) acc[i] = 0.f;

    int s0 = (q < len) ? srcs[base + q] : N;              // N = zero row
    int4 v = *reinterpret_cast<const int4*>(hb + s0 * D + l * 8);
    for (int k0 = 8; k0 < len; k0 += 8) {
        int idx = k0 + q;
        int s1 = (idx < len) ? srcs[base + idx] : N;
        int4 vn = *reinterpret_cast<const int4*>(hb + s1 * D + l * 8);
        ACC8(v);
        v = vn;
    }
    ACC8(v);

#pragma unroll
    for (int i = 0; i < 8; ++i) {
        acc[i] += __shfl_down(acc[i], 32);
        acc[i] += __shfl_down(acc[i], 16);
        acc[i] += __shfl_down(acc[i], 8);
    }
    if (lane < 8) {                        // lanes 0..7 hold dims lane*8..+7
        int4 vt = *reinterpret_cast<const int4*>(hb + t * D + lane * 8);
        ACC8(vt);
        float dt = rsqrtf((float)(len + 1));
        float4 ba = *reinterpret_cast<const float4*>(&bias[lane * 8]);
        float4 bb = *reinterpret_cast<const float4*>(&bias[lane * 8 + 4]);
        float4 o0, o1;
        o0.x = fmaf(dt, acc[0], ba.x);
        o0.y = fmaf(dt, acc[1], ba.y);
        o0.z = fmaf(dt, acc[2], ba.z);
        o0.w = fmaf(dt, acc[3], ba.w);
        o1.x = fmaf(dt, acc[4], bb.x);
        o1.y = fmaf(dt, acc[5], bb.y);
        o1.z = fmaf(dt, acc[6], bb.z);
        o1.w = fmaf(dt, acc[7], bb.w);
        *reinterpret_cast<float4*>(out + t * D + lane * 8) = o0;
        *reinterpret_cast<float4*>(out + t * D + lane * 8 + 4) = o1;
    }
}

extern "C" void kernel_launch(void* const* d_in, const int* in_sizes, int n_in,
                              void* d_out, int out_size, void* d_ws, size_t ws_size,
                              hipStream_t stream) {
    const float* x    = (const float*)d_in[0];   // [N, 64]
    const int*   ei   = (const int*)d_in[1];     // [2, E]
    const float* w    = (const float*)d_in[2];   // [64, 64]
    const float* bias = (const float*)d_in[3];   // [64]
    float* out = (float*)d_out;                  // [N, 64]

    // workspace layout (16B aligned)
    char* ws = (char*)d_ws;
    int*    gcur = (int*)(ws);                   // NB ints          @ 0
    ushort* wbf  = (ushort*)(ws + 1664);         // 4096 bf16 (8 KB)
    int*    part = (int*)(ws + 9856);            // NB*CAP ints
    int*    srcs = (int*)(ws + 4814464);         // NB*CAP ints
    int*    cnt  = (int*)(ws + 9619072);         // N ints
    int*    rs   = (int*)(ws + 10019072);        // N ints
    ushort* hb   = (ushort*)(ws + 10419072);     // (N+1)*64 bf16

    hipMemsetAsync(gcur, 0, 1664, stream);
    k_part  <<<PART_BLOCKS, 256, 0, stream>>>(ei, w, gcur, part, wbf);
    k_csr   <<<NB, 512, 0, stream>>>(gcur, part, cnt, rs, srcs);
    k_linear<<<(N + 63) / 64, 256, 0, stream>>>(x, wbf, cnt, hb);
    k_agg   <<<(N * 64) / 256, 256, 0, stream>>>(rs, cnt, srcs, hb, bias, out);
}

// Round 9
// 83.387 us; speedup vs baseline: 7.1255x; 1.0646x over previous
//
#include <hip/hip_runtime.h>
#include <hip/hip_bf16.h>

static constexpr int N = 100000;   // nodes
static constexpr int E = 1000000;  // edges
static constexpr int D = 64;       // feature dim
static constexpr int NB = 391;     // dst buckets of 256 nodes (391*256 >= N)
static constexpr int CAP = 3072;   // per-bucket edge capacity (mean 2560, ~+10 sigma)
static constexpr int PART_EPT = 8;
static constexpr int PART_CHUNK = 256 * PART_EPT;                        // 2048
static constexpr int PART_BLOCKS = (E + PART_CHUNK - 1) / PART_CHUNK;    // 489
static constexpr int LIN_BLOCKS = (N + 63) / 64;                         // 1563

typedef __attribute__((ext_vector_type(8))) short bf16x8;
typedef __attribute__((ext_vector_type(4))) float f32x4;

__device__ inline ushort f2bf(float f) {     // RNE f32 -> bf16 bits
    unsigned u = __float_as_uint(f);
    return (ushort)((u + 0x7fffu + ((u >> 16) & 1u)) >> 16);
}

// ---- init: zero gcur, W f32->bf16, dummy row N, dis[N] --------------------
__global__ __launch_bounds__(256) void k_init(const float* __restrict__ w,
                                              int* __restrict__ gcur,
                                              float* __restrict__ dis,
                                              ushort* __restrict__ wbf,
                                              ushort* __restrict__ hb) {
    int tid = threadIdx.x;
    int i0 = tid * 16;
#pragma unroll
    for (int c = 0; c < 4; ++c) {
        float4 v = *reinterpret_cast<const float4*>(w + i0 + c * 4);
        ushort4 o;
        o.x = f2bf(v.x); o.y = f2bf(v.y); o.z = f2bf(v.z); o.w = f2bf(v.w);
        *reinterpret_cast<ushort4*>(wbf + i0 + c * 4) = o;
    }
    for (int b = tid; b < NB; b += 256) gcur[b] = 0;
    if (tid == 0) dis[N] = 0.f;
    if (tid < 32) reinterpret_cast<int*>(hb + N * D)[tid] = 0;   // zero row N
}

// ---- K1: bucket partition (blocks [0,PART_BLOCKS)) ∪ linear (rest) --------
// part: part[...] = src | (dst&255)<<17, grouped per (block,bucket).
// linear: hb[n,:] = bf16(x[n,:] @ W^T), UNSCALED (dis applied in k_agg).
__global__ __launch_bounds__(256) void k_partlin(const int* __restrict__ ei,
                                                 const float* __restrict__ x,
                                                 const ushort* __restrict__ wbf,
                                                 int* __restrict__ gcur,
                                                 int* __restrict__ part,
                                                 ushort* __restrict__ hb) {
    __shared__ int hcnt[NB];
    __shared__ int hcur[NB];
    int tid = threadIdx.x;
    if (blockIdx.x < PART_BLOCKS) {
        // ---------------- partition path ----------------
        for (int b = tid; b < NB; b += 256) hcnt[b] = 0;
        __syncthreads();
        int base = blockIdx.x * PART_CHUNK + tid;
        int ss[PART_EPT], tt[PART_EPT];
#pragma unroll
        for (int k = 0; k < PART_EPT; ++k) {      // phase A: local histogram
            int i = base + k * 256;
            int s = -1, t = 0;
            if (i < E) {
                s = ei[i];
                t = ei[E + i];
                if (s == t) s = -1;               // drop self loops
            }
            ss[k] = s; tt[k] = t;
            if (s >= 0) atomicAdd(&hcnt[t >> 8], 1);
        }
        __syncthreads();
        for (int b = tid; b < NB; b += 256) {     // phase B: reserve ranges
            int c = hcnt[b];
            hcur[b] = b * CAP + (c ? atomicAdd(&gcur[b], c) : 0);
        }
        __syncthreads();
#pragma unroll
        for (int k = 0; k < PART_EPT; ++k) {      // phase C: grouped scatter
            int s = ss[k];
            if (s >= 0) {
                int b = tt[k] >> 8;
                int pos = atomicAdd(&hcur[b], 1);
                if (pos < (b + 1) * CAP)          // safety, statistically never
                    part[pos] = s | ((tt[k] & 255) << 17);
            }
        }
    } else {
        // ---------------- MFMA linear path ----------------
        int lane = tid & 63, wave = tid >> 6;
        int tbase = (blockIdx.x - PART_BLOCKS) * 64 + wave * 16;
        if (tbase >= N) return;                   // wave-uniform
        int r15 = lane & 15, g4 = lane >> 4;
        int arow = tbase + r15;
        if (arow >= N) arow = N - 1;              // clamped load, store guarded
        bf16x8 afr[2];
#pragma unroll
        for (int ks = 0; ks < 2; ++ks) {
            const float* ap = x + arow * 64 + ks * 32 + g4 * 8;
            float4 v0 = *reinterpret_cast<const float4*>(ap);
            float4 v1 = *reinterpret_cast<const float4*>(ap + 4);
            bf16x8 a;
            a[0] = (short)f2bf(v0.x); a[1] = (short)f2bf(v0.y);
            a[2] = (short)f2bf(v0.z); a[3] = (short)f2bf(v0.w);
            a[4] = (short)f2bf(v1.x); a[5] = (short)f2bf(v1.y);
            a[6] = (short)f2bf(v1.z); a[7] = (short)f2bf(v1.w);
            afr[ks] = a;
        }
        f32x4 acc[4] = {};
#pragma unroll
        for (int nt = 0; nt < 4; ++nt)
#pragma unroll
            for (int ks = 0; ks < 2; ++ks) {
                bf16x8 b = *reinterpret_cast<const bf16x8*>(
                    wbf + (nt * 16 + r15) * 64 + ks * 32 + g4 * 8);
                acc[nt] = __builtin_amdgcn_mfma_f32_16x16x32_bf16(afr[ks], b, acc[nt], 0, 0, 0);
            }
#pragma unroll
        for (int r = 0; r < 4; ++r) {
            int node = tbase + g4 * 4 + r;
            if (node < N) {
#pragma unroll
                for (int nt = 0; nt < 4; ++nt)
                    hb[node * D + nt * 16 + r15] = f2bf(acc[nt][r]);
            }
        }
    }
}

// ---- per-bucket CSR build in LDS: hist -> scan -> scatter; emits dis ------
__global__ __launch_bounds__(512) void k_csr(const int* __restrict__ gcur,
                                             const int* __restrict__ part,
                                             int* __restrict__ cnt,
                                             int* __restrict__ row_start,
                                             int* __restrict__ srcs,
                                             float* __restrict__ dis) {
    __shared__ int cntL[256];
    __shared__ int scanL[256];
    __shared__ int curL[256];
    int tid = threadIdx.x;
    int b = blockIdx.x;
    if (tid < 256) cntL[tid] = 0;
    __syncthreads();
    int en = gcur[b];
    en = en < CAP ? en : CAP;
    const int* pb = part + b * CAP;
    for (int i = tid; i < en; i += 512)
        atomicAdd(&cntL[pb[i] >> 17], 1);
    __syncthreads();
    if (tid < 256) scanL[tid] = cntL[tid];
    __syncthreads();
    for (int off = 1; off < 256; off <<= 1) {   // inclusive scan over 256
        int v = 0;
        if (tid < 256 && tid >= off) v = scanL[tid - off];
        __syncthreads();
        if (tid < 256) scanL[tid] += v;
        __syncthreads();
    }
    if (tid < 256) {
        int node = b * 256 + tid;
        int excl = scanL[tid] - cntL[tid];
        if (node < N) {
            row_start[node] = b * CAP + excl;
            cnt[node] = cntL[tid];
            dis[node] = rsqrtf((float)(cntL[tid] + 1));
        }
        curL[tid] = excl;
    }
    __syncthreads();
    for (int i = tid; i < en; i += 512) {
        int e = pb[i];
        int pos = atomicAdd(&curL[e >> 17], 1);
        srcs[b * CAP + pos] = e & 0x1FFFF;
    }
}

// ---- aggregate: one wave per node, software-pipelined gather --------------
// Octet q handles edge k0+q; lane loads 16B (8 bf16 dims) of that edge's
// UNSCALED row plus a broadcast dis[s]; fmaf folds the scale at no extra cost.
#define FMACC8(d, v)                                                        \
    acc[0] = fmaf(d, __uint_as_float(((unsigned)(v).x) << 16), acc[0]);     \
    acc[1] = fmaf(d, __uint_as_float(((unsigned)(v).x) & 0xffff0000u), acc[1]); \
    acc[2] = fmaf(d, __uint_as_float(((unsigned)(v).y) << 16), acc[2]);     \
    acc[3] = fmaf(d, __uint_as_float(((unsigned)(v).y) & 0xffff0000u), acc[3]); \
    acc[4] = fmaf(d, __uint_as_float(((unsigned)(v).z) << 16), acc[4]);     \
    acc[5] = fmaf(d, __uint_as_float(((unsigned)(v).z) & 0xffff0000u), acc[5]); \
    acc[6] = fmaf(d, __uint_as_float(((unsigned)(v).w) << 16), acc[6]);     \
    acc[7] = fmaf(d, __uint_as_float(((unsigned)(v).w) & 0xffff0000u), acc[7]);

__global__ __launch_bounds__(256) void k_agg(const int* __restrict__ row_start,
                                             const int* __restrict__ cnt,
                                             const int* __restrict__ srcs,
                                             const ushort* __restrict__ hb,
                                             const float* __restrict__ dis,
                                             const float* __restrict__ bias,
                                             float* __restrict__ out) {
    int g = blockIdx.x * 256 + threadIdx.x;
    int t = g >> 6, lane = g & 63;
    if (t >= N) return;
    int q = lane >> 3, l = lane & 7;
    int base = row_start[t];
    int len = cnt[t];
    float acc[8];
#pragma unroll
    for (int i = 0; i < 8; ++i) acc[i] = 0.f;

    int s0 = (q < len) ? srcs[base + q] : N;              // N = zero row
    float d0 = dis[s0];
    int4 v = *reinterpret_cast<const int4*>(hb + s0 * D + l * 8);
    for (int k0 = 8; k0 < len; k0 += 8) {
        int idx = k0 + q;
        int s1 = (idx < len) ? srcs[base + idx] : N;
        float d1 = dis[s1];
        int4 vn = *reinterpret_cast<const int4*>(hb + s1 * D + l * 8);
        FMACC8(d0, v);
        d0 = d1; v = vn;
    }
    FMACC8(d0, v);

#pragma unroll
    for (int i = 0; i < 8; ++i) {
        acc[i] += __shfl_down(acc[i], 32);
        acc[i] += __shfl_down(acc[i], 16);
        acc[i] += __shfl_down(acc[i], 8);
    }
    if (lane < 8) {                        // lanes 0..7 hold dims lane*8..+7
        float dt = rsqrtf((float)(len + 1));
        int4 vt = *reinterpret_cast<const int4*>(hb + t * D + lane * 8);
        FMACC8(dt, vt);                    // self message dt*h[t]
        float4 ba = *reinterpret_cast<const float4*>(&bias[lane * 8]);
        float4 bb = *reinterpret_cast<const float4*>(&bias[lane * 8 + 4]);
        float4 o0, o1;
        o0.x = fmaf(dt, acc[0], ba.x);
        o0.y = fmaf(dt, acc[1], ba.y);
        o0.z = fmaf(dt, acc[2], ba.z);
        o0.w = fmaf(dt, acc[3], ba.w);
        o1.x = fmaf(dt, acc[4], bb.x);
        o1.y = fmaf(dt, acc[5], bb.y);
        o1.z = fmaf(dt, acc[6], bb.z);
        o1.w = fmaf(dt, acc[7], bb.w);
        *reinterpret_cast<float4*>(out + t * D + lane * 8) = o0;
        *reinterpret_cast<float4*>(out + t * D + lane * 8 + 4) = o1;
    }
}

extern "C" void kernel_launch(void* const* d_in, const int* in_sizes, int n_in,
                              void* d_out, int out_size, void* d_ws, size_t ws_size,
                              hipStream_t stream) {
    const float* x    = (const float*)d_in[0];   // [N, 64]
    const int*   ei   = (const int*)d_in[1];     // [2, E]
    const float* w    = (const float*)d_in[2];   // [64, 64]
    const float* bias = (const float*)d_in[3];   // [64]
    float* out = (float*)d_out;                  // [N, 64]

    // workspace layout (16B aligned)
    char* ws = (char*)d_ws;
    int*    gcur = (int*)(ws);                   // NB ints          @ 0
    ushort* wbf  = (ushort*)(ws + 1664);         // 4096 bf16 (8 KB)
    int*    part = (int*)(ws + 9856);            // NB*CAP ints
    int*    srcs = (int*)(ws + 4814464);         // NB*CAP ints
    int*    cnt  = (int*)(ws + 9619072);         // N ints
    int*    rs   = (int*)(ws + 10019072);        // N ints
    float*  dis  = (float*)(ws + 10419072);      // N+1 floats
    ushort* hb   = (ushort*)(ws + 10819200);     // (N+1)*64 bf16

    k_init   <<<1, 256, 0, stream>>>(w, gcur, dis, wbf, hb);
    k_partlin<<<PART_BLOCKS + LIN_BLOCKS, 256, 0, stream>>>(ei, x, wbf, gcur, part, hb);
    k_csr    <<<NB, 512, 0, stream>>>(gcur, part, cnt, rs, srcs, dis);
    k_agg    <<<(N * 64) / 256, 256, 0, stream>>>(rs, cnt, srcs, hb, dis, bias, out);
}

// Round 10
// 78.721 us; speedup vs baseline: 7.5479x; 1.0593x over previous
//
#include <hip/hip_runtime.h>
#include <hip/hip_bf16.h>

static constexpr int N = 100000;   // nodes
static constexpr int E = 1000000;  // edges
static constexpr int D = 64;       // feature dim
static constexpr int NB = 391;     // dst buckets of 256 nodes (391*256 >= N)
static constexpr int CAP = 3072;   // per-bucket edge capacity (mean 2560, ~+10 sigma)
static constexpr int PART_EPT = 8;
static constexpr int PART_CHUNK = 256 * PART_EPT;                        // 2048
static constexpr int PART_BLOCKS = (E + PART_CHUNK - 1) / PART_CHUNK;    // 489
static constexpr int LIN_BLOCKS = (N + 63) / 64;                         // 1563

typedef __attribute__((ext_vector_type(8))) short bf16x8;
typedef __attribute__((ext_vector_type(4))) float f32x4;

__device__ inline ushort f2bf(float f) {     // RNE f32 -> bf16 bits
    unsigned u = __float_as_uint(f);
    return (ushort)((u + 0x7fffu + ((u >> 16) & 1u)) >> 16);
}

// ---- init: zero gcur, W f32->bf16, dummy row N, dis[N] --------------------
__global__ __launch_bounds__(256) void k_init(const float* __restrict__ w,
                                              int* __restrict__ gcur,
                                              float* __restrict__ dis,
                                              ushort* __restrict__ wbf,
                                              ushort* __restrict__ hb) {
    int tid = threadIdx.x;
    int i0 = tid * 16;
#pragma unroll
    for (int c = 0; c < 4; ++c) {
        float4 v = *reinterpret_cast<const float4*>(w + i0 + c * 4);
        ushort4 o;
        o.x = f2bf(v.x); o.y = f2bf(v.y); o.z = f2bf(v.z); o.w = f2bf(v.w);
        *reinterpret_cast<ushort4*>(wbf + i0 + c * 4) = o;
    }
    for (int b = tid; b < NB; b += 256) gcur[b] = 0;
    if (tid == 0) dis[N] = 0.f;
    if (tid < 32) reinterpret_cast<int*>(hb + N * D)[tid] = 0;   // zero row N
}

// ---- K1: bucket partition (blocks [0,PART_BLOCKS)) ∪ linear (rest) --------
__global__ __launch_bounds__(256) void k_partlin(const int* __restrict__ ei,
                                                 const float* __restrict__ x,
                                                 const ushort* __restrict__ wbf,
                                                 int* __restrict__ gcur,
                                                 int* __restrict__ part,
                                                 ushort* __restrict__ hb) {
    __shared__ int hcnt[NB];
    __shared__ int hcur[NB];
    int tid = threadIdx.x;
    if (blockIdx.x < PART_BLOCKS) {
        // ---------------- partition path ----------------
        for (int b = tid; b < NB; b += 256) hcnt[b] = 0;
        __syncthreads();
        int base = blockIdx.x * PART_CHUNK + tid;
        int ss[PART_EPT], tt[PART_EPT];
#pragma unroll
        for (int k = 0; k < PART_EPT; ++k) {      // phase A: local histogram
            int i = base + k * 256;
            int s = -1, t = 0;
            if (i < E) {
                s = ei[i];
                t = ei[E + i];
                if (s == t) s = -1;               // drop self loops
            }
            ss[k] = s; tt[k] = t;
            if (s >= 0) atomicAdd(&hcnt[t >> 8], 1);
        }
        __syncthreads();
        for (int b = tid; b < NB; b += 256) {     // phase B: reserve ranges
            int c = hcnt[b];
            hcur[b] = b * CAP + (c ? atomicAdd(&gcur[b], c) : 0);
        }
        __syncthreads();
#pragma unroll
        for (int k = 0; k < PART_EPT; ++k) {      // phase C: grouped scatter
            int s = ss[k];
            if (s >= 0) {
                int b = tt[k] >> 8;
                int pos = atomicAdd(&hcur[b], 1);
                if (pos < (b + 1) * CAP)          // safety, statistically never
                    part[pos] = s | ((tt[k] & 255) << 17);
            }
        }
    } else {
        // ---------------- MFMA linear path ----------------
        int lane = tid & 63, wave = tid >> 6;
        int tbase = (blockIdx.x - PART_BLOCKS) * 64 + wave * 16;
        if (tbase >= N) return;                   // wave-uniform
        int r15 = lane & 15, g4 = lane >> 4;
        int arow = tbase + r15;
        if (arow >= N) arow = N - 1;              // clamped load, store guarded
        bf16x8 afr[2];
#pragma unroll
        for (int ks = 0; ks < 2; ++ks) {
            const float* ap = x + arow * 64 + ks * 32 + g4 * 8;
            float4 v0 = *reinterpret_cast<const float4*>(ap);
            float4 v1 = *reinterpret_cast<const float4*>(ap + 4);
            bf16x8 a;
            a[0] = (short)f2bf(v0.x); a[1] = (short)f2bf(v0.y);
            a[2] = (short)f2bf(v0.z); a[3] = (short)f2bf(v0.w);
            a[4] = (short)f2bf(v1.x); a[5] = (short)f2bf(v1.y);
            a[6] = (short)f2bf(v1.z); a[7] = (short)f2bf(v1.w);
            afr[ks] = a;
        }
        f32x4 acc[4] = {};
#pragma unroll
        for (int nt = 0; nt < 4; ++nt)
#pragma unroll
            for (int ks = 0; ks < 2; ++ks) {
                bf16x8 b = *reinterpret_cast<const bf16x8*>(
                    wbf + (nt * 16 + r15) * 64 + ks * 32 + g4 * 8);
                acc[nt] = __builtin_amdgcn_mfma_f32_16x16x32_bf16(afr[ks], b, acc[nt], 0, 0, 0);
            }
#pragma unroll
        for (int r = 0; r < 4; ++r) {
            int node = tbase + g4 * 4 + r;
            if (node < N) {
#pragma unroll
                for (int nt = 0; nt < 4; ++nt)
                    hb[node * D + nt * 16 + r15] = f2bf(acc[nt][r]);
            }
        }
    }
}

// ---- per-bucket CSR build in LDS; emits rc=(start,cnt) and dis ------------
__global__ __launch_bounds__(512) void k_csr(const int* __restrict__ gcur,
                                             const int* __restrict__ part,
                                             int2* __restrict__ rc,
                                             int* __restrict__ srcs,
                                             float* __restrict__ dis) {
    __shared__ int cntL[256];
    __shared__ int scanL[256];
    __shared__ int curL[256];
    int tid = threadIdx.x;
    int b = blockIdx.x;
    if (tid < 256) cntL[tid] = 0;
    __syncthreads();
    int en = gcur[b];
    en = en < CAP ? en : CAP;
    const int* pb = part + b * CAP;
    for (int i = tid; i < en; i += 512)
        atomicAdd(&cntL[pb[i] >> 17], 1);
    __syncthreads();
    if (tid < 256) scanL[tid] = cntL[tid];
    __syncthreads();
    for (int off = 1; off < 256; off <<= 1) {   // inclusive scan over 256
        int v = 0;
        if (tid < 256 && tid >= off) v = scanL[tid - off];
        __syncthreads();
        if (tid < 256) scanL[tid] += v;
        __syncthreads();
    }
    if (tid < 256) {
        int node = b * 256 + tid;
        int excl = scanL[tid] - cntL[tid];
        if (node < N) {
            rc[node] = make_int2(b * CAP + excl, cntL[tid]);
            dis[node] = rsqrtf((float)(cntL[tid] + 1));
        }
        curL[tid] = excl;
    }
    __syncthreads();
    for (int i = tid; i < en; i += 512) {
        int e = pb[i];
        int pos = atomicAdd(&curL[e >> 17], 1);
        srcs[b * CAP + pos] = e & 0x1FFFF;
    }
}

// ---- aggregate: one wave per node, 2-deep software-pipelined gather -------
// Octet q handles edge k0+q; lane loads 16B (8 bf16 dims). Two rounds'
// srcs/dis/row chains in flight; self-row/bias/dt hoisted before the loop.
#define FMACC8(d, v)                                                        \
    acc[0] = fmaf(d, __uint_as_float(((unsigned)(v).x) << 16), acc[0]);     \
    acc[1] = fmaf(d, __uint_as_float(((unsigned)(v).x) & 0xffff0000u), acc[1]); \
    acc[2] = fmaf(d, __uint_as_float(((unsigned)(v).y) << 16), acc[2]);     \
    acc[3] = fmaf(d, __uint_as_float(((unsigned)(v).y) & 0xffff0000u), acc[3]); \
    acc[4] = fmaf(d, __uint_as_float(((unsigned)(v).z) << 16), acc[4]);     \
    acc[5] = fmaf(d, __uint_as_float(((unsigned)(v).z) & 0xffff0000u), acc[5]); \
    acc[6] = fmaf(d, __uint_as_float(((unsigned)(v).w) << 16), acc[6]);     \
    acc[7] = fmaf(d, __uint_as_float(((unsigned)(v).w) & 0xffff0000u), acc[7]);

__global__ __launch_bounds__(256) void k_agg(const int2* __restrict__ rc,
                                             const int* __restrict__ srcs,
                                             const ushort* __restrict__ hb,
                                             const float* __restrict__ dis,
                                             const float* __restrict__ bias,
                                             float* __restrict__ out) {
    int g = blockIdx.x * 256 + threadIdx.x;
    int t = g >> 6, lane = g & 63;
    if (t >= N) return;
    int q = lane >> 3, l = lane & 7;
    int2 bc = rc[t];
    int base = bc.x, len = bc.y;

    // hoisted tail loads: self row, bias, dt (latency hides under the loop)
    int lb = lane & 7;
    int4 vt = *reinterpret_cast<const int4*>(hb + t * D + lb * 8);
    float4 ba = *reinterpret_cast<const float4*>(&bias[lb * 8]);
    float4 bb = *reinterpret_cast<const float4*>(&bias[lb * 8 + 4]);
    float dt = rsqrtf((float)(len + 1));

    float acc[8];
#pragma unroll
    for (int i = 0; i < 8; ++i) acc[i] = 0.f;

    // 2-deep pipeline: rounds 0 and 1 issued up front
    int s0 = (q < len) ? srcs[base + q] : N;              // N = zero row
    int s1 = (8 + q < len) ? srcs[base + 8 + q] : N;
    float d0 = dis[s0];
    int4  v0 = *reinterpret_cast<const int4*>(hb + s0 * D + l * 8);
    float d1 = dis[s1];
    int4  v1 = *reinterpret_cast<const int4*>(hb + s1 * D + l * 8);
    for (int k0 = 16; k0 < len; k0 += 8) {
        int idx = k0 + q;
        int s2 = (idx < len) ? srcs[base + idx] : N;
        float d2 = dis[s2];
        int4  v2 = *reinterpret_cast<const int4*>(hb + s2 * D + l * 8);
        FMACC8(d0, v0);
        d0 = d1; v0 = v1;
        d1 = d2; v1 = v2;
    }
    FMACC8(d0, v0);
    FMACC8(d1, v1);

#pragma unroll
    for (int i = 0; i < 8; ++i) {
        acc[i] += __shfl_down(acc[i], 32);
        acc[i] += __shfl_down(acc[i], 16);
        acc[i] += __shfl_down(acc[i], 8);
    }
    if (lane < 8) {                        // lanes 0..7 hold dims lane*8..+7
        FMACC8(dt, vt);                    // self message dt*h[t]
        float4 o0, o1;
        o0.x = fmaf(dt, acc[0], ba.x);
        o0.y = fmaf(dt, acc[1], ba.y);
        o0.z = fmaf(dt, acc[2], ba.z);
        o0.w = fmaf(dt, acc[3], ba.w);
        o1.x = fmaf(dt, acc[4], bb.x);
        o1.y = fmaf(dt, acc[5], bb.y);
        o1.z = fmaf(dt, acc[6], bb.z);
        o1.w = fmaf(dt, acc[7], bb.w);
        *reinterpret_cast<float4*>(out + t * D + lane * 8) = o0;
        *reinterpret_cast<float4*>(out + t * D + lane * 8 + 4) = o1;
    }
}

extern "C" void kernel_launch(void* const* d_in, const int* in_sizes, int n_in,
                              void* d_out, int out_size, void* d_ws, size_t ws_size,
                              hipStream_t stream) {
    const float* x    = (const float*)d_in[0];   // [N, 64]
    const int*   ei   = (const int*)d_in[1];     // [2, E]
    const float* w    = (const float*)d_in[2];   // [64, 64]
    const float* bias = (const float*)d_in[3];   // [64]
    float* out = (float*)d_out;                  // [N, 64]

    // workspace layout (16B aligned)
    char* ws = (char*)d_ws;
    int*    gcur = (int*)(ws);                   // NB ints          @ 0
    ushort* wbf  = (ushort*)(ws + 1664);         // 4096 bf16 (8 KB)
    int*    part = (int*)(ws + 9856);            // NB*CAP ints
    int*    srcs = (int*)(ws + 4814464);         // NB*CAP ints
    int2*   rc   = (int2*)(ws + 9619072);        // N int2 (800 KB)
    float*  dis  = (float*)(ws + 10419072);      // N+1 floats
    ushort* hb   = (ushort*)(ws + 10819200);     // (N+1)*64 bf16

    k_init   <<<1, 256, 0, stream>>>(w, gcur, dis, wbf, hb);
    k_partlin<<<PART_BLOCKS + LIN_BLOCKS, 256, 0, stream>>>(ei, x, wbf, gcur, part, hb);
    k_csr    <<<NB, 512, 0, stream>>>(gcur, part, rc, srcs, dis);
    k_agg    <<<(N * 64) / 256, 256, 0, stream>>>(rc, srcs, hb, dis, bias, out);
}